// Round 5
// baseline (283.265 us; speedup 1.0000x reference)
//
#include <hip/hip_runtime.h>

// L1 pairwise distance: out[i][j] = sum_d |x1[i][d] - x2[j][d]|
// x1: [2048, 64] f32, x2: [2048, 64] f32, out: [2048, 2048] f32.
// Mean-adjustment cancels; clamp_min(0) is a no-op on a sum of |.|.
//
// R9 = R8 + ONE change: explicit 2-stage software pipeline on the d-loop.
// R8's counters (first time kernel crossed the top-5 cutoff): kernel
// 43.5us, VALUBusy 20%, HBM 5.7%, occupancy 19.6%, VGPR=68 -> pure
// latency-bound. At 68 VGPR the compiler issues ds_reads just-in-time in
// small batches -> ~120cy lgkmcnt stall every few loads, only 2 waves/SIMD
// (grid-capped) to cover. Fix via ILP, not occupancy: ping-pong register
// buffers A[2][8]/B[2][4]; issue step s+1's 12 ds_read_b128 before
// computing step s. Compute window 384 cyc/wave >> 120cy LDS latency.
// Steady state per CU per d-step: LDS 96 reads x 12cy = 1152cy (binding),
// VALU 768cy -> kernel floor ~7.7us + tails.
// Predict: kernel 43.5 -> 10-15us (VGPR ~150, VALUBusy 45-60%); total
// 71.9 -> 69.5-70.5 (harness fill+overhead floor; total = max(fill=41.5,
// kernel) + ~28us overhead per R4/R8 fit).

#define D_FIXED 64
#define BI 128   // x1 rows per block
#define BJ 64    // x2 cols per block
#define PAD 68   // rows 16B-aligned; bank shift 4/row -> <=2-way alias (free, m136)

typedef float v2f __attribute__((ext_vector_type(2)));

__global__ __launch_bounds__(256, 2)
void l1dist_kernel(const float* __restrict__ x1, const float* __restrict__ x2,
                   float* __restrict__ out, int N1, int N2) {
    __shared__ float s1[BI * PAD];  // 34816 B
    __shared__ float s2[BJ * PAD];  // 17408 B  (51KB total)

    const int tx = threadIdx.x;     // 0..15
    const int ty = threadIdx.y;     // 0..15
    const int t  = ty * 16 + tx;
    const int i0 = blockIdx.y * BI;
    const int j0 = blockIdx.x * BJ;

    // ---- one-shot staging (coalesced float4) ----
    const float* g1 = x1 + (size_t)i0 * D_FIXED;
    #pragma unroll
    for (int f = 0; f < 8; ++f) {           // 2048 float4s / 256 threads
        int idx = t + f * 256;
        int row = idx >> 4;
        int c4  = (idx & 15) << 2;
        *(float4*)(s1 + row * PAD + c4) = *(const float4*)(g1 + row * D_FIXED + c4);
    }
    const float* g2 = x2 + (size_t)j0 * D_FIXED;
    #pragma unroll
    for (int f = 0; f < 4; ++f) {           // 1024 float4s / 256 threads
        int idx = t + f * 256;
        int row = idx >> 4;
        int c4  = (idx & 15) << 2;
        *(float4*)(s2 + row * PAD + c4) = *(const float4*)(g2 + row * D_FIXED + c4);
    }
    __syncthreads();                         // the ONLY barrier

    // ---- 8x4 register tile: rows i = ty+16r, cols j = tx+16c ----
    float acc[8][4];
    #pragma unroll
    for (int r = 0; r < 8; ++r)
        #pragma unroll
        for (int c = 0; c < 4; ++c) acc[r][c] = 0.0f;

    // ---- 2-stage ping-pong pipeline over the 16 d-steps ----
    // All indices compile-time after full unroll (no scratch, rule #20).
    float4 A[2][8], B[2][4];
    #pragma unroll
    for (int c = 0; c < 4; ++c)              // prologue: step 0 loads
        B[0][c] = *(const float4*)(s2 + (tx + 16 * c) * PAD + 0);
    #pragma unroll
    for (int r = 0; r < 8; ++r)
        A[0][r] = *(const float4*)(s1 + (ty + 16 * r) * PAD + 0);

    #pragma unroll
    for (int s = 0; s < 16; ++s) {
        const int cur = s & 1, nxt = cur ^ 1;
        if (s < 15) {                        // issue step s+1 BEFORE computing s
            const int d = (s + 1) * 4;
            #pragma unroll
            for (int c = 0; c < 4; ++c)      // <=2-way bank alias (free)
                B[nxt][c] = *(const float4*)(s2 + (tx + 16 * c) * PAD + d);
            #pragma unroll
            for (int r = 0; r < 8; ++r)      // wave-broadcast (4 addrs/wave)
                A[nxt][r] = *(const float4*)(s1 + (ty + 16 * r) * PAD + d);
        }
        #pragma unroll
        for (int r = 0; r < 8; ++r) {
            const v2f alo = {A[cur][r].x, A[cur][r].y};
            const v2f ahi = {A[cur][r].z, A[cur][r].w};
            #pragma unroll
            for (int c = 0; c < 4; ++c) {
                const v2f blo = {B[cur][c].x, B[cur][c].y};
                const v2f bhi = {B[cur][c].z, B[cur][c].w};
                const v2f dlo = alo - blo;   // v_pk_add_f32 (neg mod): 2 elems/instr
                const v2f dhi = ahi - bhi;
                // abs folds into v_add_f32 input modifiers: 4 adds / 4 elems
                acc[r][c] += (fabsf(dlo.x) + fabsf(dlo.y)) +
                             (fabsf(dhi.x) + fabsf(dhi.y));
            }
        }
    }

    // ---- store: write-once output -> nontemporal; 64B segments per line ----
    #pragma unroll
    for (int r = 0; r < 8; ++r) {
        const size_t i = i0 + ty + 16 * r;
        #pragma unroll
        for (int c = 0; c < 4; ++c) {
            const int j = j0 + tx + 16 * c;
            __builtin_nontemporal_store(acc[r][c], &out[i * N2 + j]);
        }
    }
}

extern "C" void kernel_launch(void* const* d_in, const int* in_sizes, int n_in,
                              void* d_out, int out_size, void* d_ws, size_t ws_size,
                              hipStream_t stream) {
    const float* x1 = (const float*)d_in[0];
    const float* x2 = (const float*)d_in[1];
    float* out = (float*)d_out;

    // in_sizes[] is ELEMENT count (R4/R6-verified): 2048*64 = 131072.
    const int N1 = in_sizes[0] / D_FIXED;  // 2048
    const int N2 = in_sizes[1] / D_FIXED;  // 2048

    dim3 block(16, 16);
    dim3 grid(N2 / BJ, N1 / BI);           // (32, 16) = 512 blocks = 2/CU
    l1dist_kernel<<<grid, block, 0, stream>>>(x1, x2, out, N1, N2);
}

// Round 6
// 276.603 us; speedup vs baseline: 1.0241x; 1.0241x over previous
//
#include <hip/hip_runtime.h>

// L1 pairwise distance: out[i][j] = sum_d |x1[i][d] - x2[j][d]|
// x1: [2048, 64] f32, x2: [2048, 64] f32, out: [2048, 2048] f32.
// Mean-adjustment cancels; clamp_min(0) is a no-op on a sum of |.|.
//
// R10 = R9's 2-stage pipeline, re-encoded scratch-proof. R9's failure was
// rule #20: A[2][8]/B[2][4] indexed by cur=s&1 went to LOCAL MEMORY ->
// FETCH 342MB / WRITE 328MB of scratch traffic, VALUBusy 4.7%, 5.5x slower
// (240us). Fix: statically distinct even/odd buffers (Ae/Be, Ao/Bo),
// hand-written 2-step body; every index is a literal from a constant-trip
// unrolled loop (same pattern as R8's a[8]/b[4], which allocated fine).
// R8 diagnosis stands: 43.5us latency-bound (VALUBusy 20%, VGPR=68, JIT
// ds_read batches expose ~120cy lgkmcnt stalls; 2 waves/SIMD can't hide).
// Pipeline: step s+1's 12 ds_read_b128 (144cy LDS pipe) issue before step
// s's compute (384cy VALU issue) -> stalls covered by ILP. Budget: 24
// float4 + 32 acc + addr ~ 145 VGPR < 256 cap at launch_bounds(256,2).
// Predict: FETCH ~2.5MB WRITE ~17.4MB (no scratch -- primary check),
// kernel 43.5 -> 10-15us, VALUBusy 45-65%; total ~69.5-70.0 (fill floor:
// total = max(fill 41.5, kernel) + ~28 per R4/R8 fit).

#define D_FIXED 64
#define BI 128   // x1 rows per block
#define BJ 64    // x2 cols per block
#define PAD 68   // rows 16B-aligned; bank shift 4/row -> <=2-way alias (free, m136)

typedef float v2f __attribute__((ext_vector_type(2)));

#define LOAD_TILE(A_, B_, dd)                                              \
    {                                                                      \
        _Pragma("unroll")                                                  \
        for (int c = 0; c < 4; ++c)   /* <=2-way bank alias (free) */      \
            B_[c] = *(const float4*)(s2 + (tx + 16 * c) * PAD + (dd));     \
        _Pragma("unroll")                                                  \
        for (int r = 0; r < 8; ++r)   /* wave-broadcast (4 addrs/wave) */  \
            A_[r] = *(const float4*)(s1 + (ty + 16 * r) * PAD + (dd));     \
    }

#define COMP_TILE(A_, B_)                                                  \
    {                                                                      \
        _Pragma("unroll")                                                  \
        for (int r = 0; r < 8; ++r) {                                      \
            const v2f alo = {A_[r].x, A_[r].y};                            \
            const v2f ahi = {A_[r].z, A_[r].w};                            \
            _Pragma("unroll")                                              \
            for (int c = 0; c < 4; ++c) {                                  \
                const v2f blo = {B_[c].x, B_[c].y};                        \
                const v2f bhi = {B_[c].z, B_[c].w};                        \
                const v2f dlo = alo - blo;  /* v_pk_add_f32 (neg mod) */   \
                const v2f dhi = ahi - bhi;                                 \
                acc[r][c] += (fabsf(dlo.x) + fabsf(dlo.y)) +               \
                             (fabsf(dhi.x) + fabsf(dhi.y));                \
            }                                                              \
        }                                                                  \
    }

__global__ __launch_bounds__(256, 2)
void l1dist_kernel(const float* __restrict__ x1, const float* __restrict__ x2,
                   float* __restrict__ out, int N1, int N2) {
    __shared__ float s1[BI * PAD];  // 34816 B
    __shared__ float s2[BJ * PAD];  // 17408 B  (51KB total)

    const int tx = threadIdx.x;     // 0..15
    const int ty = threadIdx.y;     // 0..15
    const int t  = ty * 16 + tx;
    const int i0 = blockIdx.y * BI;
    const int j0 = blockIdx.x * BJ;

    // ---- one-shot staging (coalesced float4) ----
    const float* g1 = x1 + (size_t)i0 * D_FIXED;
    #pragma unroll
    for (int f = 0; f < 8; ++f) {           // 2048 float4s / 256 threads
        int idx = t + f * 256;
        int row = idx >> 4;
        int c4  = (idx & 15) << 2;
        *(float4*)(s1 + row * PAD + c4) = *(const float4*)(g1 + row * D_FIXED + c4);
    }
    const float* g2 = x2 + (size_t)j0 * D_FIXED;
    #pragma unroll
    for (int f = 0; f < 4; ++f) {           // 1024 float4s / 256 threads
        int idx = t + f * 256;
        int row = idx >> 4;
        int c4  = (idx & 15) << 2;
        *(float4*)(s2 + row * PAD + c4) = *(const float4*)(g2 + row * D_FIXED + c4);
    }
    __syncthreads();                         // the ONLY barrier

    // ---- 8x4 register tile: rows i = ty+16r, cols j = tx+16c ----
    float acc[8][4];
    #pragma unroll
    for (int r = 0; r < 8; ++r)
        #pragma unroll
        for (int c = 0; c < 4; ++c) acc[r][c] = 0.0f;

    // ---- 2-stage pipeline, statically distinct even/odd buffers ----
    float4 Ae[8], Be[4], Ao[8], Bo[4];
    LOAD_TILE(Ae, Be, 0);                    // prologue: step 0

    #pragma unroll
    for (int s = 0; s < 16; s += 2) {        // 2 d-steps per iteration
        LOAD_TILE(Ao, Bo, (s + 1) * 4);      // issue s+1 before computing s
        COMP_TILE(Ae, Be);
        if (s + 2 < 16)
            LOAD_TILE(Ae, Be, (s + 2) * 4);  // issue s+2 before computing s+1
        COMP_TILE(Ao, Bo);
    }

    // ---- store: write-once output -> nontemporal; 64B segments per line ----
    #pragma unroll
    for (int r = 0; r < 8; ++r) {
        const size_t i = i0 + ty + 16 * r;
        #pragma unroll
        for (int c = 0; c < 4; ++c) {
            const int j = j0 + tx + 16 * c;
            __builtin_nontemporal_store(acc[r][c], &out[i * N2 + j]);
        }
    }
}

extern "C" void kernel_launch(void* const* d_in, const int* in_sizes, int n_in,
                              void* d_out, int out_size, void* d_ws, size_t ws_size,
                              hipStream_t stream) {
    const float* x1 = (const float*)d_in[0];
    const float* x2 = (const float*)d_in[1];
    float* out = (float*)d_out;

    // in_sizes[] is ELEMENT count (R4/R6-verified): 2048*64 = 131072.
    const int N1 = in_sizes[0] / D_FIXED;  // 2048
    const int N2 = in_sizes[1] / D_FIXED;  // 2048

    dim3 block(16, 16);
    dim3 grid(N2 / BJ, N1 / BI);           // (32, 16) = 512 blocks = 2/CU
    l1dist_kernel<<<grid, block, 0, stream>>>(x1, x2, out, N1, N2);
}

// Round 7
// 69.389 us; speedup vs baseline: 4.0823x; 3.9863x over previous
//
#include <hip/hip_runtime.h>

// L1 pairwise distance: out[i][j] = sum_d |x1[i][d] - x2[j][d]|
// x1: [2048, 64] f32, x2: [2048, 64] f32, out: [2048, 2048] f32.
// Mean-adjustment cancels; clamp_min(0) is a no-op on a sum of |.|.
//
// R11: TLP instead of ILP. R9/R10's register pipelines both went to
// scratch (FETCH/WRITE ~300MB, 230us) -- abandoned. R9/R10's long kernels
// also resolved the harness model: total = fill(41.5us) + kernel + ~5us
// (serial), so R4's plain kernel was ~23us and sub-41.5 kernel time IS
// visible in total. R8 counters: VALUBusy 20%, LDS pipe ~18% busy,
// occupancy 19.6% (2 waves/SIMD, grid-capped) -> latency-bound on JIT
// ds_read batches (~120cy each).
// Fix: 64x64 tile, 256 threads, 4x4 outputs/thread. LDS 34.8KB/block ->
// 4 blocks/CU (grid 1024 = exactly 4/CU) = 16 waves/CU = 4 waves/SIMD:
// 2x the stall interleaving, no compiler-scheduling dependence. VGPR ~55
// (16 acc + 8 in-flight float4). Inner body = R4's scalar form (R8 showed
// pk-sub neutral-to-negative: marshaling movs).
// Floors/CU: LDS 2048 ds_read_b128 x 12cy = 10.2us (binding), VALU 6.8us.
// Predict: kernel 43.5 -> 15-22us (rocprof), VALUBusy 40-55%, Occupancy
// ~40-50%, VGPR ~56, LDS 34816, FETCH ~2.5MB WRITE ~17.5MB (scratch-free);
// total 71.9 -> ~58-63 (new best). If total pins at ~69.9 instead, the
// overlap model wins -> declare roofline next round.

#define D_FIXED 64
#define BI 64    // x1 rows per block
#define BJ 64    // x2 cols per block
#define PAD 68   // rows 16B-aligned; bank shift 4/row -> <=2-way alias (free, m136)

__global__ __launch_bounds__(256, 4)
void l1dist_kernel(const float* __restrict__ x1, const float* __restrict__ x2,
                   float* __restrict__ out, int N1, int N2) {
    __shared__ float s1[BI * PAD];  // 17408 B
    __shared__ float s2[BJ * PAD];  // 17408 B  (34.8KB total -> 4 blocks/CU)

    const int tx = threadIdx.x;     // 0..15
    const int ty = threadIdx.y;     // 0..15
    const int t  = ty * 16 + tx;
    const int i0 = blockIdx.y * BI;
    const int j0 = blockIdx.x * BJ;

    // ---- one-shot staging (coalesced float4) ----
    const float* g1 = x1 + (size_t)i0 * D_FIXED;
    #pragma unroll
    for (int f = 0; f < 4; ++f) {           // 1024 float4s / 256 threads
        int idx = t + f * 256;
        int row = idx >> 4;
        int c4  = (idx & 15) << 2;
        *(float4*)(s1 + row * PAD + c4) = *(const float4*)(g1 + row * D_FIXED + c4);
    }
    const float* g2 = x2 + (size_t)j0 * D_FIXED;
    #pragma unroll
    for (int f = 0; f < 4; ++f) {           // 1024 float4s / 256 threads
        int idx = t + f * 256;
        int row = idx >> 4;
        int c4  = (idx & 15) << 2;
        *(float4*)(s2 + row * PAD + c4) = *(const float4*)(g2 + row * D_FIXED + c4);
    }
    __syncthreads();                         // the ONLY barrier

    // ---- 4x4 register tile: rows i = ty+16r, cols j = tx+16c ----
    float acc[4][4];
    #pragma unroll
    for (int r = 0; r < 4; ++r)
        #pragma unroll
        for (int c = 0; c < 4; ++c) acc[r][c] = 0.0f;

    #pragma unroll
    for (int d = 0; d < D_FIXED; d += 4) {   // FULL unroll (R3's bound regressed)
        float4 a[4], b[4];
        #pragma unroll
        for (int c = 0; c < 4; ++c)          // <=2-way bank alias (free)
            b[c] = *(const float4*)(s2 + (tx + 16 * c) * PAD + d);
        #pragma unroll
        for (int r = 0; r < 4; ++r)          // wave-broadcast (4 addrs/wave)
            a[r] = *(const float4*)(s1 + (ty + 16 * r) * PAD + d);

        #pragma unroll
        for (int r = 0; r < 4; ++r) {
            #pragma unroll
            for (int c = 0; c < 4; ++c) {
                float d0 = a[r].x - b[c].x;
                float d1 = a[r].y - b[c].y;
                float d2 = a[r].z - b[c].z;
                float d3 = a[r].w - b[c].w;
                // abs folds into v_add_f32 input modifiers: 8 VALU per 4 elems
                acc[r][c] += (fabsf(d0) + fabsf(d1)) + (fabsf(d2) + fabsf(d3));
            }
        }
    }

    // ---- store: write-once output -> nontemporal; 64B segments per line ----
    #pragma unroll
    for (int r = 0; r < 4; ++r) {
        const size_t i = i0 + ty + 16 * r;
        #pragma unroll
        for (int c = 0; c < 4; ++c) {
            const int j = j0 + tx + 16 * c;
            __builtin_nontemporal_store(acc[r][c], &out[i * N2 + j]);
        }
    }
}

extern "C" void kernel_launch(void* const* d_in, const int* in_sizes, int n_in,
                              void* d_out, int out_size, void* d_ws, size_t ws_size,
                              hipStream_t stream) {
    const float* x1 = (const float*)d_in[0];
    const float* x2 = (const float*)d_in[1];
    float* out = (float*)d_out;

    // in_sizes[] is ELEMENT count (R4/R6-verified): 2048*64 = 131072.
    const int N1 = in_sizes[0] / D_FIXED;  // 2048
    const int N2 = in_sizes[1] / D_FIXED;  // 2048

    dim3 block(16, 16);
    dim3 grid(N2 / BJ, N1 / BI);           // (32, 32) = 1024 blocks = 4/CU
    l1dist_kernel<<<grid, block, 0, stream>>>(x1, x2, out, N1, N2);
}